// Round 1
// baseline (8630.721 us; speedup 1.0000x reference)
//
#include <hip/hip_runtime.h>
#include <math.h>

#define T_STEPS 100
#define B_DIM 128
#define I_DIM 1024
#define H_DIM 4096
#define O_DIM 512

// Order-preserving float->uint map so atomicMax(uint) == float max (handles negatives).
__device__ __forceinline__ unsigned fmap(float f){
  unsigned u = __float_as_uint(f);
  return (u & 0x80000000u) ? ~u : (u | 0x80000000u);
}
__device__ __forceinline__ float funmap(unsigned m){
  unsigned u = (m & 0x80000000u) ? (m & 0x7FFFFFFFu) : ~m;
  return __uint_as_float(u);
}
// dyn_vth = vth * tanh(grad_win * max) with vth=0.3, grad_win=0.3 (both layers)
__device__ __forceinline__ float vth_of(unsigned m){
  return 0.3f * tanhf(0.3f * funmap(m));
}

__global__ __launch_bounds__(256) void init_kernel(
    float* hv0, float* hv1, float* g0, float* g1,
    float* ov0, float* ov1, float* out,
    unsigned* hmaxA, unsigned* omaxA, unsigned* ticket)
{
  int i = blockIdx.x * 256 + threadIdx.x;
  if (i < B_DIM*H_DIM) { hv0[i]=0.f; hv1[i]=0.f; g0[i]=0.f; g1[i]=0.f; }
  if (i < B_DIM*O_DIM) { ov0[i]=0.f; ov1[i]=0.f; out[i]=0.f; }
  if (i < 256) ticket[i]=0u;
  if (i < 128) {
    // slot 0 is the "step -1" max: volt==0 everywhere -> max 0 -> vth 0 -> spike(0>0)=0,
    // matching the zero initial spike state. Other slots start at -inf for atomicMax.
    unsigned v = (i==0) ? 0x80000000u : fmap(-3.0e38f);
    hmaxA[i]=v; omaxA[i]=v;
  }
}

// spike_data [B][I][T] -> XT [T][B][I] so GEMM1 reads are contiguous in i.
__global__ __launch_bounds__(256) void transpose_kernel(const float* __restrict__ sp,
                                                        float* __restrict__ XT)
{
  __shared__ float tile[64][101];   // pad 101: stride 5 mod 32 -> conflict-free
  int b  = blockIdx.x;
  int i0 = blockIdx.y * 64;
  const float* src = sp + (size_t)b * I_DIM * T_STEPS + (size_t)i0 * T_STEPS;
  for (int e = threadIdx.x; e < 64*T_STEPS; e += 256) {
    int ii = e / T_STEPS, tt = e % T_STEPS;
    tile[ii][tt] = src[(size_t)ii*T_STEPS + tt];
  }
  __syncthreads();
  for (int e = threadIdx.x; e < 64*T_STEPS; e += 256) {
    int tt = e / 64, ii = e % 64;
    XT[((size_t)tt*B_DIM + b)*I_DIM + i0 + ii] = tile[ii][tt];
  }
}

// Fused per-step kernel:
//   blocks [0,512):  GEMM1 for step t+1 (64x64 tiles, K=1024 split into 4 chunks of 256)
//                    -> atomicAdd partials into gaccW; last-finisher per tile applies
//                    decay/reset, writes hv_{t+1}, atomicMax -> hmaxA[t+2]
//   blocks [512,768): GEMM2 for step t (64x64 tiles, K=4096 split into 16 chunks of 256),
//                    A = (hv_t > vth_t) computed on the fly; chunk0 adds the
//                    ov decay/reset base, accumulates out += os_{t-1}, zeroes ov_{t-1};
//                    last-finisher per tile atomicMax -> omaxA[t+1]
__global__ __launch_bounds__(256) void step_kernel(
    const float* __restrict__ XT,
    const float* __restrict__ Wh,
    const float* __restrict__ Wo,
    const float* __restrict__ hvR,   // hv_t
    float* __restrict__ hvW,         // hv_{t+1}
    float* __restrict__ gaccW,       // GEMM1 partial accumulator (pre-zeroed)
    float* __restrict__ ovR,         // ov_{t-1} (read then zeroed by chunk0)
    float* __restrict__ ovW,         // ov_t accumulation target (pre-zeroed)
    const unsigned* __restrict__ hmax_t,  // &hmaxA[t+1]
    unsigned* __restrict__ hmax_n,        // &hmaxA[t+2]
    const unsigned* __restrict__ omax_p,  // &omaxA[max(t,0)]
    unsigned* __restrict__ omax_n,        // &omaxA[t+1]
    unsigned* __restrict__ ticket,
    float* __restrict__ out,
    int t)
{
  const int tid = threadIdx.x;
  const bool g1 = (blockIdx.x < 512);
  if (g1) { if (t >= T_STEPS-1) return; }   // no GEMM1 at last step
  else    { if (t < 0) return; }            // no GEMM2 at priming step

  __shared__ float As[16][68];   // [k][m], stride 68: 16B-aligned frags, <=2-way banks
  __shared__ float Bs[16][68];
  __shared__ float red[256];
  __shared__ unsigned sflag;

  const float hvth = vth_of(*hmax_t);

  int mb, nb, kc, tileId, nchunk, ld;
  const float* Ap; const float* Bp;
  if (g1) {
    int g = blockIdx.x;
    nb = g & 63; mb = (g >> 6) & 1; kc = g >> 7;
    tileId = mb*64 + nb; nchunk = 4; ld = I_DIM;
    Ap = XT + (size_t)(t+1)*B_DIM*I_DIM + (size_t)(mb*64)*I_DIM + kc*256;
    Bp = Wh + (size_t)(nb*64)*I_DIM + kc*256;
  } else {
    int g = blockIdx.x - 512;
    nb = g & 7; mb = (g >> 3) & 1; kc = g >> 4;
    tileId = 128 + mb*8 + nb; nchunk = 16; ld = H_DIM;
    Ap = hvR + (size_t)(mb*64)*H_DIM + kc*256;
    Bp = Wo + (size_t)(nb*64)*H_DIM + kc*256;
  }

  const int srow = tid >> 2;          // staging: row 0..63
  const int skq  = (tid & 3) << 2;    // staging: k offset 0,4,8,12
  const int tx = tid & 15, ty = tid >> 4;

  float acc[4][4];
  #pragma unroll
  for (int r=0;r<4;r++)
    #pragma unroll
    for (int c=0;c<4;c++) acc[r][c]=0.f;

  for (int kk = 0; kk < 256; kk += 16) {
    float4 av = *(const float4*)(Ap + (size_t)srow*ld + kk + skq);
    float4 bv = *(const float4*)(Bp + (size_t)srow*ld + kk + skq);
    if (!g1) {  // A operand of GEMM2 is the binary spike of hv_t
      av.x = (av.x > hvth) ? 1.f : 0.f;
      av.y = (av.y > hvth) ? 1.f : 0.f;
      av.z = (av.z > hvth) ? 1.f : 0.f;
      av.w = (av.w > hvth) ? 1.f : 0.f;
    }
    __syncthreads();
    As[skq+0][srow]=av.x; As[skq+1][srow]=av.y; As[skq+2][srow]=av.z; As[skq+3][srow]=av.w;
    Bs[skq+0][srow]=bv.x; Bs[skq+1][srow]=bv.y; Bs[skq+2][srow]=bv.z; Bs[skq+3][srow]=bv.w;
    __syncthreads();
    #pragma unroll
    for (int k=0;k<16;k++){
      float4 a = *(const float4*)&As[k][ty<<2];
      float4 b = *(const float4*)&Bs[k][tx<<2];
      acc[0][0] += a.x*b.x; acc[0][1] += a.x*b.y; acc[0][2] += a.x*b.z; acc[0][3] += a.x*b.w;
      acc[1][0] += a.y*b.x; acc[1][1] += a.y*b.y; acc[1][2] += a.y*b.z; acc[1][3] += a.y*b.w;
      acc[2][0] += a.z*b.x; acc[2][1] += a.z*b.y; acc[2][2] += a.z*b.z; acc[2][3] += a.z*b.w;
      acc[3][0] += a.w*b.x; acc[3][1] += a.w*b.y; acc[3][2] += a.w*b.z; acc[3][3] += a.w*b.w;
    }
  }

  const int r0 = mb*64 + (ty<<2);
  const int c0 = nb*64 + (tx<<2);

  if (g1) {
    #pragma unroll
    for (int r=0;r<4;r++)
      #pragma unroll
      for (int c=0;c<4;c++)
        atomicAdd(&gaccW[(size_t)(r0+r)*H_DIM + c0+c], acc[r][c]);
    __syncthreads();
    if (tid==0){ __threadfence(); sflag = atomicAdd(&ticket[tileId], 1u); }
    __syncthreads();
    if (sflag == (unsigned)(nchunk-1)) {      // last finisher of this 64x64 tile
      __threadfence();                        // acquire: see peers' atomics
      float lmax = -3.0e38f;
      #pragma unroll
      for (int r=0;r<4;r++)
        #pragma unroll
        for (int c=0;c<4;c++){
          size_t idx = (size_t)(r0+r)*H_DIM + c0+c;
          float gg = gaccW[idx];
          float h0 = hvR[idx];
          float hs = (h0 > hvth) ? 1.f : 0.f;
          float hn = 0.5f*h0*(1.f-hs) + gg;   // vdecay=0.5, reset-by-spike
          hvW[idx] = hn;
          gaccW[idx] = 0.f;                   // re-zero for reuse at step t+2
          lmax = fmaxf(lmax, hn);
        }
      red[tid]=lmax; __syncthreads();
      for (int s=128; s>0; s>>=1){ if (tid<s) red[tid]=fmaxf(red[tid],red[tid+s]); __syncthreads(); }
      if (tid==0){ atomicMax(hmax_n, fmap(red[0])); ticket[tileId]=0u; }
    }
  } else {
    if (kc==0){  // exclusive owner of this ov tile's base term + output accumulation
      float ovth = vth_of(*omax_p);
      #pragma unroll
      for (int r=0;r<4;r++)
        #pragma unroll
        for (int c=0;c<4;c++){
          size_t idx = (size_t)(r0+r)*O_DIM + c0+c;
          float o0 = ovR[idx];
          float os = (o0 > ovth) ? 1.f : 0.f;
          acc[r][c] += 0.5f*o0*(1.f-os);
          out[idx] += os;                     // sum of output spikes (os_{t-1})
          ovR[idx] = 0.f;                     // re-zero for reuse at step t+1
        }
    }
    #pragma unroll
    for (int r=0;r<4;r++)
      #pragma unroll
      for (int c=0;c<4;c++)
        atomicAdd(&ovW[(size_t)(r0+r)*O_DIM + c0+c], acc[r][c]);
    __syncthreads();
    if (tid==0){ __threadfence(); sflag = atomicAdd(&ticket[tileId], 1u); }
    __syncthreads();
    if (sflag == (unsigned)(nchunk-1)) {
      __threadfence();
      float lmax = -3.0e38f;
      #pragma unroll
      for (int r=0;r<4;r++)
        #pragma unroll
        for (int c=0;c<4;c++)
          lmax = fmaxf(lmax, ovW[(size_t)(r0+r)*O_DIM + c0+c]);
      red[tid]=lmax; __syncthreads();
      for (int s=128; s>0; s>>=1){ if (tid<s) red[tid]=fmaxf(red[tid],red[tid+s]); __syncthreads(); }
      if (tid==0){ atomicMax(omax_n, fmap(red[0])); ticket[tileId]=0u; }
    }
  }
}

// out += os_{T-1}
__global__ __launch_bounds__(256) void final_kernel(const float* __restrict__ ov,
                                                    const unsigned* __restrict__ omax_last,
                                                    float* __restrict__ out)
{
  int i = blockIdx.x*256 + threadIdx.x;
  if (i < B_DIM*O_DIM) {
    float vth = vth_of(*omax_last);
    out[i] += (ov[i] > vth) ? 1.f : 0.f;
  }
}

extern "C" void kernel_launch(void* const* d_in, const int* in_sizes, int n_in,
                              void* d_out, int out_size, void* d_ws, size_t ws_size,
                              hipStream_t stream) {
  const float* spike = (const float*)d_in[0];
  const float* Wh    = (const float*)d_in[5];   // [H, I]
  const float* Wo    = (const float*)d_in[6];   // [O, H]
  float* out = (float*)d_out;

  char* ws = (char*)d_ws;
  size_t off = 0;
  float* XT = (float*)(ws + off); off += (size_t)T_STEPS*B_DIM*I_DIM*sizeof(float);
  float* hv[2];   hv[0]  =(float*)(ws+off); off += (size_t)B_DIM*H_DIM*sizeof(float);
                  hv[1]  =(float*)(ws+off); off += (size_t)B_DIM*H_DIM*sizeof(float);
  float* gacc[2]; gacc[0]=(float*)(ws+off); off += (size_t)B_DIM*H_DIM*sizeof(float);
                  gacc[1]=(float*)(ws+off); off += (size_t)B_DIM*H_DIM*sizeof(float);
  float* ov[2];   ov[0]  =(float*)(ws+off); off += (size_t)B_DIM*O_DIM*sizeof(float);
                  ov[1]  =(float*)(ws+off); off += (size_t)B_DIM*O_DIM*sizeof(float);
  unsigned* hmaxA  = (unsigned*)(ws+off); off += 128*sizeof(unsigned);
  unsigned* omaxA  = (unsigned*)(ws+off); off += 128*sizeof(unsigned);
  unsigned* ticket = (unsigned*)(ws+off); off += 256*sizeof(unsigned);
  (void)ws_size; (void)in_sizes; (void)n_in; (void)out_size;

  init_kernel<<<(B_DIM*H_DIM)/256, 256, 0, stream>>>(
      hv[0], hv[1], gacc[0], gacc[1], ov[0], ov[1], out, hmaxA, omaxA, ticket);

  transpose_kernel<<<dim3(B_DIM, I_DIM/64), 256, 0, stream>>>(spike, XT);

  for (int t = -1; t < T_STEPS; t++) {
    step_kernel<<<768, 256, 0, stream>>>(
        XT, Wh, Wo,
        hv[(t+2)&1],        // hv_t
        hv[(t+1)&1],        // hv_{t+1}
        gacc[(t+1)&1],
        ov[(t+1)&1],        // ov_{t-1}
        ov[(t+2)&1],        // ov_t
        hmaxA + (t+1), hmaxA + (t+2),
        omaxA + (t < 0 ? 0 : t), omaxA + (t+1),
        ticket, out, t);
  }

  final_kernel<<<(B_DIM*O_DIM)/256, 256, 0, stream>>>(ov[1], omaxA + T_STEPS, out);
}